// Round 8
// baseline (4074.999 us; speedup 1.0000x reference)
//
#include <hip/hip_runtime.h>
#include <math.h>

typedef _Float16 h2_t  __attribute__((ext_vector_type(2)));
typedef _Float16 h4_t  __attribute__((ext_vector_type(4)));
typedef _Float16 h8_t  __attribute__((ext_vector_type(8)));
typedef _Float16 h32_t __attribute__((ext_vector_type(32)));
typedef float    f4_t  __attribute__((ext_vector_type(4)));

#define T_ 512
#define B_ 64
#define E_ 256
#define H_ 256
#define G_ 1024   // 4*H
#define K_ 16
#define NEG_ (-10000.0f)
#define START_ 14
#define STOP_ 15

#if defined(__has_builtin)
#if __has_builtin(__builtin_amdgcn_fdot2)
#define HAVE_FDOT2 1
#endif
#endif

static __device__ __forceinline__ float dot2(h2_t a, h2_t b, float c) {
#ifdef HAVE_FDOT2
    return __builtin_amdgcn_fdot2(a, b, c, false);
#else
    return fmaf((float)a[0], (float)b[0], fmaf((float)a[1], (float)b[1], c));
#endif
}

// R8: precise activations (R4-proven numerics). Fast-math variants are one
// of the two bisect suspects and are intentionally removed this round.
static __device__ __forceinline__ float psigmoid(float x) {
    return 1.f / (1.f + expf(-x));
}

// extract h2 pair P from a wider fp16 vector (SSA, never an alloca)
template <int P, typename V>
static __device__ __forceinline__ h2_t get2(V v) {
    return __builtin_shufflevector(v, v, 2 * P, 2 * P + 1);
}

// ---------------------------------------------------------------------------
// Prep: pack weights fp16 in hot-kernel layouts.
//  wreg2: [dir][v=0..27][q=0..255] x h32 ; v = rs*7+cc -> row q+256*rs,
//         k = cc*32 .. +32                                (896 KB)
//  wlds2: [dir][j=0..15][q=0..255] x h8  ; j = rs*4+jj -> row q+256*rs,
//         k = 224 + jj*8 .. +8                            (128 KB)
//  wih16: [dir][row][k] fp16 copy of w_ih                 (1 MB)
// ---------------------------------------------------------------------------
__global__ __launch_bounds__(256)
void prep_weights(const float* __restrict__ w_hh_f,
                  const float* __restrict__ w_hh_b,
                  const float* __restrict__ w_ih_f,
                  const float* __restrict__ w_ih_b,
                  _Float16* __restrict__ wreg2,
                  _Float16* __restrict__ wlds2,
                  _Float16* __restrict__ wih16)
{
    const int blk = blockIdx.x, tid = threadIdx.x;
    if (blk < 56) {                        // wreg2: 14336 x h32
        int idx = blk * 256 + tid;
        int dir = idx / 7168, rem = idx % 7168;
        int v = rem / 256, q = rem % 256;
        int rs = v / 7, cc = v % 7;
        const float* src = (dir ? w_hh_b : w_hh_f) + (size_t)(q + 256 * rs) * 256 + cc * 32;
        _Float16* dst = wreg2 + (size_t)idx * 32;
        #pragma unroll
        for (int i = 0; i < 32; ++i) dst[i] = (_Float16)src[i];
    } else if (blk < 88) {                 // wlds2: 8192 x h8
        int idx = (blk - 56) * 256 + tid;
        int dir = idx / 4096, rem = idx % 4096;
        int j = rem / 256, q = rem % 256;
        int rs = j / 4, jj = j % 4;
        const float* src = (dir ? w_hh_b : w_hh_f) + (size_t)(q + 256 * rs) * 256 + 224 + jj * 8;
        _Float16* dst = wlds2 + (size_t)idx * 8;
        #pragma unroll
        for (int i = 0; i < 8; ++i) dst[i] = (_Float16)src[i];
    } else {                               // wih16: 65536 x h8
        int idx = (blk - 88) * 256 + tid;
        int dir = idx / 32768, rem = idx % 32768;
        const float* src = (dir ? w_ih_b : w_ih_f) + (size_t)rem * 8;
        _Float16* dst = wih16 + (size_t)idx * 8;
        #pragma unroll
        for (int i = 0; i < 8; ++i) dst[i] = (_Float16)src[i];
    }
}

// ---------------------------------------------------------------------------
// Kernel A: input-gate GEMM via f16 MFMA 16x16x32. Block = (t, dir).
// OUTPUT RELAYOUT: gate-row n lands at position (n&255)*4 + (n>>8)
// -> unit-major, 4 gates contiguous (one h4 per unit).
// ---------------------------------------------------------------------------
__global__ __launch_bounds__(256)
void gates_mfma(const int* __restrict__ sentence,
                const float* __restrict__ emb,
                const _Float16* __restrict__ wih16,
                _Float16* __restrict__ gin_f,
                _Float16* __restrict__ gin_b)
{
    __shared__ _Float16 As[64 * 264];
    __shared__ _Float16 Bs[256 * 40];
    __shared__ int sidx[64];

    const int bm  = blockIdx.x;           // t
    const int dir = blockIdx.y;
    const int tid = threadIdx.x;

    const _Float16* __restrict__ wih = wih16 + (size_t)dir * 262144;
    _Float16* __restrict__ gout      = dir ? gin_b : gin_f;

    if (tid < 64) sidx[tid] = sentence[tid * T_ + bm];
    __syncthreads();

    {   // stage A (emb gather, fp32 -> fp16)
        const int r = tid & 63, kq = tid >> 6;
        const float4* src = (const float4*)(emb + (size_t)sidx[r] * 256 + kq * 64);
        _Float16* dst = As + r * 264 + kq * 64;
        #pragma unroll
        for (int c = 0; c < 8; ++c) {
            float4 v0 = src[2 * c], v1 = src[2 * c + 1];
            h8_t o;
            o[0] = (_Float16)v0.x; o[1] = (_Float16)v0.y;
            o[2] = (_Float16)v0.z; o[3] = (_Float16)v0.w;
            o[4] = (_Float16)v1.x; o[5] = (_Float16)v1.y;
            o[6] = (_Float16)v1.z; o[7] = (_Float16)v1.w;
            *(h8_t*)(dst + c * 8) = o;
        }
    }

    const int wave = tid >> 6, lane = tid & 63;
    const int l15 = lane & 15, quad = lane >> 4;

    for (int pass = 0; pass < 4; ++pass) {
        const int n0 = pass * 256;
        f4_t acc[16];
        #pragma unroll
        for (int nt = 0; nt < 16; ++nt) acc[nt] = (f4_t){0.f, 0.f, 0.f, 0.f};

        for (int kc = 0; kc < 8; ++kc) {
            __syncthreads();
            {
                const h8_t* bsrc = (const h8_t*)(wih + (size_t)(n0 + tid) * 256 + kc * 32);
                #pragma unroll
                for (int c = 0; c < 4; ++c)
                    *(h8_t*)(Bs + tid * 40 + c * 8) = bsrc[c];
            }
            __syncthreads();
            h8_t a = *(const h8_t*)(As + (wave * 16 + l15) * 264 + kc * 32 + quad * 8);
            #pragma unroll
            for (int nt = 0; nt < 16; ++nt) {
                h8_t b = *(const h8_t*)(Bs + (nt * 16 + l15) * 40 + quad * 8);
                acc[nt] = __builtin_amdgcn_mfma_f32_16x16x32_f16(a, b, acc[nt], 0, 0, 0);
            }
        }

        const size_t mbase = (size_t)bm * 64 + wave * 16 + quad * 4;
        #pragma unroll
        for (int nt = 0; nt < 16; ++nt) {
            const int col = n0 + nt * 16 + l15;
            const int pos = ((col & 255) << 2) | (col >> 8);   // unit-major
            #pragma unroll
            for (int r = 0; r < 4; ++r)
                gout[(mbase + r) * 1024 + pos] = (_Float16)acc[nt][r];
        }
    }
}

// ---------------------------------------------------------------------------
// Kernel B: persistent LSTM. 128 blocks = (dir, b), 256 threads,
// __launch_bounds__(256,1) -> 512 VGPR cap. Thread q owns unit q's 4 gate
// rows {q, q+256, q+512, q+768}: k<224 in 28 h32 SSA values (448 VGPRs),
// k in [224,256) from LDS. Activation thread-local; h double-buffered.
// R8 BISECT: plain __syncthreads() (not the custom lgkm-only barrier) and
// precise expf/tanhf activations — the two remaining R5-introduced suspects.
// ---------------------------------------------------------------------------
#define DOTV(ACC, W, HV, P0) do {                                             \
    ACC = dot2(get2<(P0) + 0>(W), get2<0>(HV), ACC);                          \
    ACC = dot2(get2<(P0) + 1>(W), get2<1>(HV), ACC);                          \
    ACC = dot2(get2<(P0) + 2>(W), get2<2>(HV), ACC);                          \
    ACC = dot2(get2<(P0) + 3>(W), get2<3>(HV), ACC);                          \
} while (0)

#define CHUNK(WI, WF, WG, WO, CC) do {                                        \
    h8_t v0 = HB[4 * (CC) + 0], v1 = HB[4 * (CC) + 1];                        \
    h8_t v2 = HB[4 * (CC) + 2], v3 = HB[4 * (CC) + 3];                        \
    DOTV(a0, WI, v0, 0); DOTV(a0, WI, v1, 4); DOTV(a0, WI, v2, 8); DOTV(a0, WI, v3, 12); \
    DOTV(a1, WF, v0, 0); DOTV(a1, WF, v1, 4); DOTV(a1, WF, v2, 8); DOTV(a1, WF, v3, 12); \
    DOTV(a2, WG, v0, 0); DOTV(a2, WG, v1, 4); DOTV(a2, WG, v2, 8); DOTV(a2, WG, v3, 12); \
    DOTV(a3, WO, v0, 0); DOTV(a3, WO, v1, 4); DOTV(a3, WO, v2, 8); DOTV(a3, WO, v3, 12); \
} while (0)

__global__ __launch_bounds__(256, 1)
void lstm_persist(const _Float16* __restrict__ gin_f,
                  const _Float16* __restrict__ gin_b,
                  const _Float16* __restrict__ wreg2,
                  const _Float16* __restrict__ wlds2,
                  const float* __restrict__ b_f,
                  const float* __restrict__ b_b,
                  float* __restrict__ hf, float* __restrict__ hb)
{
    __shared__ h8_t wsh[4096];        // 64 KB weight tail (k 224..255)
    __shared__ h8_t hbA[32], hbB[32]; // double-buffered h (256 fp16 each)

    const int dir = blockIdx.x >> 6;
    const int b   = blockIdx.x & 63;
    const int q   = threadIdx.x;      // unit index

    const _Float16* __restrict__ gin = dir ? gin_b : gin_f;
    const float*    __restrict__ bs  = dir ? b_b : b_f;
    float*          __restrict__ hout = dir ? hb : hf;

    {   // stage LDS weight tail (16 h8 per thread), stride j*256
        const h8_t* src = (const h8_t*)wlds2 + (size_t)dir * 4096 + q;
        #pragma unroll
        for (int j = 0; j < 16; ++j) wsh[j * 256 + q] = src[(size_t)j * 256];
    }

    // 28 h32 register-resident weight chunks (448 VGPRs)
    const h32_t* wr = (const h32_t*)wreg2 + (size_t)dir * 7168 + q;
    h32_t W00 = wr[0*256],  W01 = wr[1*256],  W02 = wr[2*256],  W03 = wr[3*256];
    h32_t W04 = wr[4*256],  W05 = wr[5*256],  W06 = wr[6*256],  W07 = wr[7*256];
    h32_t W08 = wr[8*256],  W09 = wr[9*256],  W10 = wr[10*256], W11 = wr[11*256];
    h32_t W12 = wr[12*256], W13 = wr[13*256], W14 = wr[14*256], W15 = wr[15*256];
    h32_t W16 = wr[16*256], W17 = wr[17*256], W18 = wr[18*256], W19 = wr[19*256];
    h32_t W20 = wr[20*256], W21 = wr[21*256], W22 = wr[22*256], W23 = wr[23*256];
    h32_t W24 = wr[24*256], W25 = wr[25*256], W26 = wr[26*256], W27 = wr[27*256];

    const float bi = bs[q], bf2 = bs[q + 256], bg = bs[q + 512], bo = bs[q + 768];

    if (q < 32) {
        h8_t z = (h8_t)(_Float16)0.f;
        hbA[q] = z; hbB[q] = z;
    }
    float c = 0.f;
    __syncthreads();

    const int t0 = dir ? 511 : 0;
    const int gstep4 = dir ? -16384 : 16384;          // gin h4-stride per t
    const long hstep  = dir ? -(64 * 256) : (64 * 256);
    const h4_t* gp4 = (const h4_t*)gin + (size_t)t0 * 16384 + (size_t)b * 256 + q;
    float*      hp  = hout + (size_t)t0 * (64 * 256) + (size_t)b * 256 + q;

    const h8_t* HBa = hbA;
    const h8_t* HBb = hbB;

    h4_t g4 = gp4[0];

    for (int s = 0; s < T_; ++s) {
        const h8_t* HB = (s & 1) ? HBb : HBa;
        h8_t* HN = (s & 1) ? (h8_t*)hbA : (h8_t*)hbB;

        h4_t g4n = gp4[gstep4];                        // prefetch next step

        float a0 = bi  + (float)g4[0];
        float a1 = bf2 + (float)g4[1];
        float a2 = bg  + (float)g4[2];
        float a3 = bo  + (float)g4[3];

        CHUNK(W00, W07, W14, W21, 0);
        CHUNK(W01, W08, W15, W22, 1);
        CHUNK(W02, W09, W16, W23, 2);
        CHUNK(W03, W10, W17, W24, 3);
        CHUNK(W04, W11, W18, W25, 4);
        CHUNK(W05, W12, W19, W26, 5);
        CHUNK(W06, W13, W20, W27, 6);

        {   // LDS tail: k in [224,256)
            h8_t u0 = HB[28], u1 = HB[29], u2 = HB[30], u3 = HB[31];
            h8_t t00 = wsh[0*256+q],  t01 = wsh[1*256+q],  t02 = wsh[2*256+q],  t03 = wsh[3*256+q];
            h8_t t10 = wsh[4*256+q],  t11 = wsh[5*256+q],  t12 = wsh[6*256+q],  t13 = wsh[7*256+q];
            h8_t t20 = wsh[8*256+q],  t21 = wsh[9*256+q],  t22 = wsh[10*256+q], t23 = wsh[11*256+q];
            h8_t t30 = wsh[12*256+q], t31 = wsh[13*256+q], t32 = wsh[14*256+q], t33 = wsh[15*256+q];
            DOTV(a0, t00, u0, 0); DOTV(a0, t01, u1, 0); DOTV(a0, t02, u2, 0); DOTV(a0, t03, u3, 0);
            DOTV(a1, t10, u0, 0); DOTV(a1, t11, u1, 0); DOTV(a1, t12, u2, 0); DOTV(a1, t13, u3, 0);
            DOTV(a2, t20, u0, 0); DOTV(a2, t21, u1, 0); DOTV(a2, t22, u2, 0); DOTV(a2, t23, u3, 0);
            DOTV(a3, t30, u0, 0); DOTV(a3, t31, u1, 0); DOTV(a3, t32, u2, 0); DOTV(a3, t33, u3, 0);
        }

        // activation — precise (R4 numerics)
        float si = psigmoid(a0);
        float sf = psigmoid(a1);
        float so = psigmoid(a3);
        c = sf * c + si * tanhf(a2);
        float h = so * tanhf(c);

        hp[0] = h;
        ((_Float16*)HN)[q] = (_Float16)h;

        g4 = g4n;
        gp4 += gstep4;
        hp  += hstep;

        __syncthreads();   // full barrier (R4-proven); custom barrier removed
    }
}

// ---------------------------------------------------------------------------
// Kernel C: feats[m, o] = concat(hf[m], hb[m]) . w_out[o, :] + b_out[o]
// ---------------------------------------------------------------------------
__global__ __launch_bounds__(256)
void feats_proj(const float* __restrict__ hf, const float* __restrict__ hb,
                const float* __restrict__ w_out, const float* __restrict__ b_out,
                float* __restrict__ feats)
{
    const int lane = threadIdx.x & 63;
    const int wv   = threadIdx.x >> 6;
    const int m    = blockIdx.x * 4 + wv;
    const int o    = lane & 15;
    const int qq   = lane >> 4;

    const float* hsrc = (qq < 2) ? (hf + (size_t)m * 256 + qq * 128)
                                 : (hb + (size_t)m * 256 + (qq - 2) * 128);
    const float4* h4 = (const float4*)hsrc;
    const float4* w4 = (const float4*)(w_out + o * 512 + qq * 128);

    float acc = 0.f;
    #pragma unroll
    for (int i = 0; i < 32; ++i) {
        float4 hv = h4[i], wvv = w4[i];
        acc = fmaf(hv.x, wvv.x, acc);
        acc = fmaf(hv.y, wvv.y, acc);
        acc = fmaf(hv.z, wvv.z, acc);
        acc = fmaf(hv.w, wvv.w, acc);
    }
    acc += __shfl_xor(acc, 16, 64);
    acc += __shfl_xor(acc, 32, 64);
    if (lane < 16) feats[(size_t)m * 16 + o] = acc + b_out[o];
}

// ---------------------------------------------------------------------------
// Kernel D: Viterbi + backtrace. One wave per batch element.
// ---------------------------------------------------------------------------
__global__ __launch_bounds__(64)
void viterbi(const float* __restrict__ feats, const float* __restrict__ trans,
             float* __restrict__ out)
{
    __shared__ unsigned char bp[T_][16];
    const int b    = blockIdx.x;
    const int lane = threadIdx.x;
    const int l15  = lane & 15;

    float tr[16];
    #pragma unroll
    for (int p = 0; p < 16; ++p)
        tr[p] = (lane < 16) ? trans[lane * 16 + p] : 0.f;

    float fv = (lane == START_) ? 0.f : NEG_;

    for (int t4 = 0; t4 < T_; t4 += 4) {
        float fblk = feats[((size_t)(t4 + (lane >> 4)) * 64 + b) * 16 + l15];
        #pragma unroll
        for (int tt = 0; tt < 4; ++tt) {
            const int t = t4 + tt;
            float best = -3.4e38f; int arg = 0;
            #pragma unroll
            for (int p = 0; p < 16; ++p) {
                float s = __shfl(fv, p, 64) + tr[p];
                if (s > best) { best = s; arg = p; }
            }
            float ft = __shfl(fblk, tt * 16 + l15, 64);
            if (lane < 16) {
                fv = best + ft;
                bp[t][lane] = (unsigned char)arg;
            }
        }
    }

    float term = fv + ((lane < 16) ? trans[STOP_ * 16 + lane] : 0.f);
    float v  = (lane < 16) ? term : -3.4e38f;
    int  idx = (lane < 16) ? lane : (1 << 20);
    #pragma unroll
    for (int off = 1; off < 64; off <<= 1) {
        float v2 = __shfl_xor(v, off, 64);
        int   i2 = __shfl_xor(idx, off, 64);
        if (v2 > v || (v2 == v && i2 < idx)) { v = v2; idx = i2; }
    }
    __syncthreads();
    if (lane == 0) {
        out[b] = v;
        int tag = idx;
        for (int t = T_ - 1; t >= 0; --t) {
            out[64 + (size_t)t * 64 + b] = (float)tag;
            tag = bp[t][tag];
        }
    }
}

// ---------------------------------------------------------------------------
extern "C" void kernel_launch(void* const* d_in, const int* in_sizes, int n_in,
                              void* d_out, int out_size, void* d_ws, size_t ws_size,
                              hipStream_t stream) {
    const int*   sentence = (const int*)d_in[0];
    const float* emb      = (const float*)d_in[1];
    const float* w_ih_f   = (const float*)d_in[2];
    const float* w_hh_f   = (const float*)d_in[3];
    const float* b_f      = (const float*)d_in[4];
    const float* w_ih_b   = (const float*)d_in[5];
    const float* w_hh_b   = (const float*)d_in[6];
    const float* b_b      = (const float*)d_in[7];
    const float* w_out    = (const float*)d_in[8];
    const float* b_out    = (const float*)d_in[9];
    const float* trans    = (const float*)d_in[10];
    float* out = (float*)d_out;

    // workspace: gin_f|gin_b fp16 (64MB ea) | hf|hb fp32 (32MB ea) |
    //            feats (2MB) | wreg2 (896KB) | wlds2 (128KB) | wih16 (1MB)
    _Float16* gin_f = (_Float16*)d_ws;
    _Float16* gin_b = gin_f + (size_t)T_ * B_ * G_;
    float* hf    = (float*)(gin_b + (size_t)T_ * B_ * G_);
    float* hb    = hf + (size_t)T_ * B_ * H_;
    float* feats = hb + (size_t)T_ * B_ * H_;
    _Float16* wreg2 = (_Float16*)(feats + (size_t)T_ * B_ * K_);
    _Float16* wlds2 = wreg2 + 458752;
    _Float16* wih16 = wlds2 + 65536;

    prep_weights<<<344, 256, 0, stream>>>(w_hh_f, w_hh_b, w_ih_f, w_ih_b,
                                          wreg2, wlds2, wih16);
    gates_mfma<<<dim3(512, 2), 256, 0, stream>>>(sentence, emb, wih16,
                                                 gin_f, gin_b);
    lstm_persist<<<128, 256, 0, stream>>>(gin_f, gin_b, wreg2, wlds2,
                                          b_f, b_b, hf, hb);
    feats_proj<<<8192, 256, 0, stream>>>(hf, hb, w_out, b_out, feats);
    viterbi<<<64, 64, 0, stream>>>(feats, trans, out);
}

// Round 9
// 1729.442 us; speedup vs baseline: 2.3563x; 2.3563x over previous
//
#include <hip/hip_runtime.h>
#include <math.h>

typedef _Float16 h2_t  __attribute__((ext_vector_type(2)));
typedef _Float16 h8_t  __attribute__((ext_vector_type(8)));
typedef _Float16 h32_t __attribute__((ext_vector_type(32)));
typedef float    f4_t  __attribute__((ext_vector_type(4)));

#define T_ 512
#define B_ 64
#define E_ 256
#define H_ 256
#define G_ 1024   // 4*H
#define K_ 16
#define NEG_ (-10000.0f)
#define START_ 14
#define STOP_ 15

#if defined(__has_builtin)
#if __has_builtin(__builtin_amdgcn_fdot2)
#define HAVE_FDOT2 1
#endif
#endif

static __device__ __forceinline__ float dot2(h2_t a, h2_t b, float c) {
#ifdef HAVE_FDOT2
    return __builtin_amdgcn_fdot2(a, b, c, false);
#else
    return fmaf((float)a[0], (float)b[0], fmaf((float)a[1], (float)b[1], c));
#endif
}

static __device__ __forceinline__ float psigmoid(float x) {
    return 1.f / (1.f + expf(-x));   // precise (R8-proven numerics)
}

// extract h2 pair P from a wider fp16 vector (SSA, never an alloca)
template <int P, typename V>
static __device__ __forceinline__ h2_t get2(V v) {
    return __builtin_shufflevector(v, v, 2 * P, 2 * P + 1);
}

// ---------------------------------------------------------------------------
// Prep: pack weights fp16.
//  wreg3: [dir][v=0..11][q=0..511] x h32 ; v<6: row q, k=v*32;
//         v>=6: row q+512, k=(v-6)*32                       (768 KB)
//  wlds3: [dir][j=0..15][q=0..511] x h8 ; j=rs*8+jj -> row q+512*rs,
//         k = 192 + jj*8                                    (256 KB)
//  wih16: [dir][row][k] fp16 copy of w_ih                   (1 MB)
// ---------------------------------------------------------------------------
__global__ __launch_bounds__(256)
void prep_weights(const float* __restrict__ w_hh_f,
                  const float* __restrict__ w_hh_b,
                  const float* __restrict__ w_ih_f,
                  const float* __restrict__ w_ih_b,
                  _Float16* __restrict__ wreg3,
                  _Float16* __restrict__ wlds3,
                  _Float16* __restrict__ wih16)
{
    const int blk = blockIdx.x, tid = threadIdx.x;
    if (blk < 48) {                        // wreg3: 12288 x h32
        int idx = blk * 256 + tid;
        int dir = idx / 6144, rem = idx % 6144;
        int v = rem / 512, q = rem % 512;
        int row = (v < 6) ? q : q + 512;
        int kb = (v % 6) * 32;
        const float* src = (dir ? w_hh_b : w_hh_f) + (size_t)row * 256 + kb;
        _Float16* dst = wreg3 + (size_t)idx * 32;
        #pragma unroll
        for (int i = 0; i < 32; ++i) dst[i] = (_Float16)src[i];
    } else if (blk < 112) {                // wlds3: 16384 x h8
        int idx = (blk - 48) * 256 + tid;
        int dir = idx / 8192, rem = idx % 8192;
        int j = rem / 512, q = rem % 512;
        int rs = j / 8, jj = j % 8;
        int row = q + 512 * rs;
        const float* src = (dir ? w_hh_b : w_hh_f) + (size_t)row * 256 + 192 + jj * 8;
        _Float16* dst = wlds3 + (size_t)idx * 8;
        #pragma unroll
        for (int i = 0; i < 8; ++i) dst[i] = (_Float16)src[i];
    } else {                               // wih16: 65536 x h8
        int idx = (blk - 112) * 256 + tid;
        int dir = idx / 32768, rem = idx % 32768;
        const float* src = (dir ? w_ih_b : w_ih_f) + (size_t)rem * 8;
        _Float16* dst = wih16 + (size_t)idx * 8;
        #pragma unroll
        for (int i = 0; i < 8; ++i) dst[i] = (_Float16)src[i];
    }
}

// ---------------------------------------------------------------------------
// Kernel A: input-gate GEMM via f16 MFMA 16x16x32. Block = (t, dir).
// OUTPUT RELAYOUT (R9): gate-row n -> position (n&511)*2 | (n>>9), so the
// lstm thread q reads rows {q, q+512} as ONE h2 at h2-index q.
// ---------------------------------------------------------------------------
__global__ __launch_bounds__(256)
void gates_mfma(const int* __restrict__ sentence,
                const float* __restrict__ emb,
                const _Float16* __restrict__ wih16,
                _Float16* __restrict__ gin_f,
                _Float16* __restrict__ gin_b)
{
    __shared__ _Float16 As[64 * 264];
    __shared__ _Float16 Bs[256 * 40];
    __shared__ int sidx[64];

    const int bm  = blockIdx.x;           // t
    const int dir = blockIdx.y;
    const int tid = threadIdx.x;

    const _Float16* __restrict__ wih = wih16 + (size_t)dir * 262144;
    _Float16* __restrict__ gout      = dir ? gin_b : gin_f;

    if (tid < 64) sidx[tid] = sentence[tid * T_ + bm];
    __syncthreads();

    {   // stage A (emb gather, fp32 -> fp16)
        const int r = tid & 63, kq = tid >> 6;
        const float4* src = (const float4*)(emb + (size_t)sidx[r] * 256 + kq * 64);
        _Float16* dst = As + r * 264 + kq * 64;
        #pragma unroll
        for (int c = 0; c < 8; ++c) {
            float4 v0 = src[2 * c], v1 = src[2 * c + 1];
            h8_t o;
            o[0] = (_Float16)v0.x; o[1] = (_Float16)v0.y;
            o[2] = (_Float16)v0.z; o[3] = (_Float16)v0.w;
            o[4] = (_Float16)v1.x; o[5] = (_Float16)v1.y;
            o[6] = (_Float16)v1.z; o[7] = (_Float16)v1.w;
            *(h8_t*)(dst + c * 8) = o;
        }
    }

    const int wave = tid >> 6, lane = tid & 63;
    const int l15 = lane & 15, quad = lane >> 4;

    for (int pass = 0; pass < 4; ++pass) {
        const int n0 = pass * 256;
        f4_t acc[16];
        #pragma unroll
        for (int nt = 0; nt < 16; ++nt) acc[nt] = (f4_t){0.f, 0.f, 0.f, 0.f};

        for (int kc = 0; kc < 8; ++kc) {
            __syncthreads();
            {
                const h8_t* bsrc = (const h8_t*)(wih + (size_t)(n0 + tid) * 256 + kc * 32);
                #pragma unroll
                for (int c = 0; c < 4; ++c)
                    *(h8_t*)(Bs + tid * 40 + c * 8) = bsrc[c];
            }
            __syncthreads();
            h8_t a = *(const h8_t*)(As + (wave * 16 + l15) * 264 + kc * 32 + quad * 8);
            #pragma unroll
            for (int nt = 0; nt < 16; ++nt) {
                h8_t b = *(const h8_t*)(Bs + (nt * 16 + l15) * 40 + quad * 8);
                acc[nt] = __builtin_amdgcn_mfma_f32_16x16x32_f16(a, b, acc[nt], 0, 0, 0);
            }
        }

        const size_t mbase = (size_t)bm * 64 + wave * 16 + quad * 4;
        #pragma unroll
        for (int nt = 0; nt < 16; ++nt) {
            const int col = n0 + nt * 16 + l15;
            const int pos = ((col & 511) << 1) | (col >> 9);   // pair-major
            #pragma unroll
            for (int r = 0; r < 4; ++r)
                gout[(mbase + r) * 1024 + pos] = (_Float16)acc[nt][r];
        }
    }
}

// ---------------------------------------------------------------------------
// Kernel B: persistent LSTM. 128 blocks = (dir, b), 512 threads,
// __launch_bounds__(512,2) -> 2 waves/SIMD, 256-VGPR cap. Thread q owns
// gate rows {q, q+512}: k<192 in 12 h32 SSA values (192 VGPRs — fits the
// cap, unlike R8's 448), k in [192,256) streamed from LDS (128 KB).
// Activation via gbuf exchange (R2/R4-proven), 2 full __syncthreads/step,
// precise expf/tanhf (R8-proven). Global h-store after barrier 2.
// ---------------------------------------------------------------------------
#define DOTV(ACC, W, HV, P0) do {                                             \
    ACC = dot2(get2<(P0) + 0>(W), get2<0>(HV), ACC);                          \
    ACC = dot2(get2<(P0) + 1>(W), get2<1>(HV), ACC);                          \
    ACC = dot2(get2<(P0) + 2>(W), get2<2>(HV), ACC);                          \
    ACC = dot2(get2<(P0) + 3>(W), get2<3>(HV), ACC);                          \
} while (0)

#define CHUNK2(W, X, CC) do {                                                 \
    h8_t v0 = hsh[4 * (CC) + 0], v1 = hsh[4 * (CC) + 1];                      \
    h8_t v2 = hsh[4 * (CC) + 2], v3 = hsh[4 * (CC) + 3];                      \
    DOTV(a0, W, v0, 0); DOTV(a0, W, v1, 4); DOTV(a0, W, v2, 8); DOTV(a0, W, v3, 12); \
    DOTV(a1, X, v0, 0); DOTV(a1, X, v1, 4); DOTV(a1, X, v2, 8); DOTV(a1, X, v3, 12); \
} while (0)

__global__ __launch_bounds__(512, 2)
void lstm_persist(const _Float16* __restrict__ gin_f,
                  const _Float16* __restrict__ gin_b,
                  const _Float16* __restrict__ wreg3,
                  const _Float16* __restrict__ wlds3,
                  const float* __restrict__ b_f,
                  const float* __restrict__ b_b,
                  float* __restrict__ hf, float* __restrict__ hb)
{
    __shared__ h8_t  wsh[8192];       // 128 KB weight tail (k 192..255)
    __shared__ float gbuf[1024];
    __shared__ h8_t  hsh[32];         // 256 h values fp16

    const int dir = blockIdx.x >> 6;
    const int b   = blockIdx.x & 63;
    const int q   = threadIdx.x;      // 0..511

    const _Float16* __restrict__ gin = dir ? gin_b : gin_f;
    const float*    __restrict__ bs  = dir ? b_b : b_f;
    float*          __restrict__ hout = dir ? hb : hf;

    {   // stage LDS weight tail (16 h8 per thread)
        const h8_t* src = (const h8_t*)wlds3 + (size_t)dir * 8192 + q;
        #pragma unroll
        for (int j = 0; j < 16; ++j) wsh[j * 512 + q] = src[(size_t)j * 512];
    }

    // 12 h32 register-resident weight chunks (192 VGPRs)
    const h32_t* wr = (const h32_t*)wreg3 + (size_t)dir * 6144 + q;
    h32_t W0 = wr[0 * 512], W1 = wr[1 * 512], W2 = wr[2 * 512];
    h32_t W3 = wr[3 * 512], W4 = wr[4 * 512], W5 = wr[5 * 512];
    h32_t X0 = wr[6 * 512], X1 = wr[7 * 512], X2 = wr[8 * 512];
    h32_t X3 = wr[9 * 512], X4 = wr[10 * 512], X5 = wr[11 * 512];

    const float bi = bs[q];           // row q     (gate i or f)
    const float bx = bs[q + 512];     // row q+512 (gate g or o)

    if (q < 32) hsh[q] = (h8_t)(_Float16)0.f;
    float c = 0.f;
    __syncthreads();

    const int t0 = dir ? 511 : 0;
    const int gstep2 = dir ? -32768 : 32768;          // gin h2-stride per t
    const long hstep  = dir ? -(64 * 256) : (64 * 256);
    const h2_t* gp2 = (const h2_t*)gin + (size_t)t0 * 32768 + (size_t)b * 512 + q;
    float*      hp  = hout + (size_t)t0 * (64 * 256) + (size_t)b * 256 + q;

    h2_t g2 = gp2[0];

    for (int s = 0; s < T_; ++s) {
        h2_t g2n = gp2[gstep2];                        // prefetch next step

        float a0 = bi + (float)g2[0];
        float a1 = bx + (float)g2[1];

        CHUNK2(W0, X0, 0); CHUNK2(W1, X1, 1); CHUNK2(W2, X2, 2);
        CHUNK2(W3, X3, 3); CHUNK2(W4, X4, 4); CHUNK2(W5, X5, 5);

        {   // LDS tail: k in [192,256)
            h8_t u0 = hsh[24], u1 = hsh[25], u2 = hsh[26], u3 = hsh[27];
            h8_t u4 = hsh[28], u5 = hsh[29], u6 = hsh[30], u7 = hsh[31];
            h8_t t0w = wsh[0*512+q],  t1w = wsh[1*512+q],  t2w = wsh[2*512+q],  t3w = wsh[3*512+q];
            h8_t t4w = wsh[4*512+q],  t5w = wsh[5*512+q],  t6w = wsh[6*512+q],  t7w = wsh[7*512+q];
            DOTV(a0, t0w, u0, 0); DOTV(a0, t1w, u1, 0); DOTV(a0, t2w, u2, 0); DOTV(a0, t3w, u3, 0);
            DOTV(a0, t4w, u4, 0); DOTV(a0, t5w, u5, 0); DOTV(a0, t6w, u6, 0); DOTV(a0, t7w, u7, 0);
            h8_t s0w = wsh[8*512+q],  s1w = wsh[9*512+q],  s2w = wsh[10*512+q], s3w = wsh[11*512+q];
            h8_t s4w = wsh[12*512+q], s5w = wsh[13*512+q], s6w = wsh[14*512+q], s7w = wsh[15*512+q];
            DOTV(a1, s0w, u0, 0); DOTV(a1, s1w, u1, 0); DOTV(a1, s2w, u2, 0); DOTV(a1, s3w, u3, 0);
            DOTV(a1, s4w, u4, 0); DOTV(a1, s5w, u5, 0); DOTV(a1, s6w, u6, 0); DOTV(a1, s7w, u7, 0);
        }

        gbuf[q] = a0;          // rows q      : gates i (q<256), f (q>=256)
        gbuf[q + 512] = a1;    // rows q+512  : gates g (q<256), o (q>=256)
        __syncthreads();       // barrier 1

        float h = 0.f;
        if (q < 256) {
            float gi = gbuf[q], gf = gbuf[q + 256], gg = gbuf[q + 512], go = gbuf[q + 768];
            float si = psigmoid(gi);
            float sf = psigmoid(gf);
            float so = psigmoid(go);
            c = sf * c + si * tanhf(gg);
            h = so * tanhf(c);
            ((_Float16*)hsh)[q] = (_Float16)h;
        }
        __syncthreads();       // barrier 2 (h visible for next dot phase)

        if (q < 256) hp[0] = h;   // global store AFTER barrier: ack overlaps
        hp += hstep;              // next step's dot phase

        g2 = g2n;
        gp2 += gstep2;
    }
}

// ---------------------------------------------------------------------------
// Kernel C: feats[m, o] = concat(hf[m], hb[m]) . w_out[o, :] + b_out[o]
// ---------------------------------------------------------------------------
__global__ __launch_bounds__(256)
void feats_proj(const float* __restrict__ hf, const float* __restrict__ hb,
                const float* __restrict__ w_out, const float* __restrict__ b_out,
                float* __restrict__ feats)
{
    const int lane = threadIdx.x & 63;
    const int wv   = threadIdx.x >> 6;
    const int m    = blockIdx.x * 4 + wv;
    const int o    = lane & 15;
    const int qq   = lane >> 4;

    const float* hsrc = (qq < 2) ? (hf + (size_t)m * 256 + qq * 128)
                                 : (hb + (size_t)m * 256 + (qq - 2) * 128);
    const float4* h4 = (const float4*)hsrc;
    const float4* w4 = (const float4*)(w_out + o * 512 + qq * 128);

    float acc = 0.f;
    #pragma unroll
    for (int i = 0; i < 32; ++i) {
        float4 hv = h4[i], wvv = w4[i];
        acc = fmaf(hv.x, wvv.x, acc);
        acc = fmaf(hv.y, wvv.y, acc);
        acc = fmaf(hv.z, wvv.z, acc);
        acc = fmaf(hv.w, wvv.w, acc);
    }
    acc += __shfl_xor(acc, 16, 64);
    acc += __shfl_xor(acc, 32, 64);
    if (lane < 16) feats[(size_t)m * 16 + o] = acc + b_out[o];
}

// ---------------------------------------------------------------------------
// Kernel D: Viterbi + backtrace. One wave per batch element.
// ---------------------------------------------------------------------------
__global__ __launch_bounds__(64)
void viterbi(const float* __restrict__ feats, const float* __restrict__ trans,
             float* __restrict__ out)
{
    __shared__ unsigned char bp[T_][16];
    const int b    = blockIdx.x;
    const int lane = threadIdx.x;
    const int l15  = lane & 15;

    float tr[16];
    #pragma unroll
    for (int p = 0; p < 16; ++p)
        tr[p] = (lane < 16) ? trans[lane * 16 + p] : 0.f;

    float fv = (lane == START_) ? 0.f : NEG_;

    for (int t4 = 0; t4 < T_; t4 += 4) {
        float fblk = feats[((size_t)(t4 + (lane >> 4)) * 64 + b) * 16 + l15];
        #pragma unroll
        for (int tt = 0; tt < 4; ++tt) {
            const int t = t4 + tt;
            float best = -3.4e38f; int arg = 0;
            #pragma unroll
            for (int p = 0; p < 16; ++p) {
                float s = __shfl(fv, p, 64) + tr[p];
                if (s > best) { best = s; arg = p; }
            }
            float ft = __shfl(fblk, tt * 16 + l15, 64);
            if (lane < 16) {
                fv = best + ft;
                bp[t][lane] = (unsigned char)arg;
            }
        }
    }

    float term = fv + ((lane < 16) ? trans[STOP_ * 16 + lane] : 0.f);
    float v  = (lane < 16) ? term : -3.4e38f;
    int  idx = (lane < 16) ? lane : (1 << 20);
    #pragma unroll
    for (int off = 1; off < 64; off <<= 1) {
        float v2 = __shfl_xor(v, off, 64);
        int   i2 = __shfl_xor(idx, off, 64);
        if (v2 > v || (v2 == v && i2 < idx)) { v = v2; idx = i2; }
    }
    __syncthreads();
    if (lane == 0) {
        out[b] = v;
        int tag = idx;
        for (int t = T_ - 1; t >= 0; --t) {
            out[64 + (size_t)t * 64 + b] = (float)tag;
            tag = bp[t][tag];
        }
    }
}

// ---------------------------------------------------------------------------
extern "C" void kernel_launch(void* const* d_in, const int* in_sizes, int n_in,
                              void* d_out, int out_size, void* d_ws, size_t ws_size,
                              hipStream_t stream) {
    const int*   sentence = (const int*)d_in[0];
    const float* emb      = (const float*)d_in[1];
    const float* w_ih_f   = (const float*)d_in[2];
    const float* w_hh_f   = (const float*)d_in[3];
    const float* b_f      = (const float*)d_in[4];
    const float* w_ih_b   = (const float*)d_in[5];
    const float* w_hh_b   = (const float*)d_in[6];
    const float* b_b      = (const float*)d_in[7];
    const float* w_out    = (const float*)d_in[8];
    const float* b_out    = (const float*)d_in[9];
    const float* trans    = (const float*)d_in[10];
    float* out = (float*)d_out;

    // workspace: gin_f|gin_b fp16 (64MB ea) | hf|hb fp32 (32MB ea) |
    //            feats (2MB) | wreg3 (768KB) | wlds3 (256KB) | wih16 (1MB)
    _Float16* gin_f = (_Float16*)d_ws;
    _Float16* gin_b = gin_f + (size_t)T_ * B_ * G_;
    float* hf    = (float*)(gin_b + (size_t)T_ * B_ * G_);
    float* hb    = hf + (size_t)T_ * B_ * H_;
    float* feats = hb + (size_t)T_ * B_ * H_;
    _Float16* wreg3 = (_Float16*)(feats + (size_t)T_ * B_ * K_);
    _Float16* wlds3 = wreg3 + 393216;
    _Float16* wih16 = wlds3 + 131072;

    prep_weights<<<368, 256, 0, stream>>>(w_hh_f, w_hh_b, w_ih_f, w_ih_b,
                                          wreg3, wlds3, wih16);
    gates_mfma<<<dim3(512, 2), 256, 0, stream>>>(sentence, emb, wih16,
                                                 gin_f, gin_b);
    lstm_persist<<<128, 512, 0, stream>>>(gin_f, gin_b, wreg3, wlds3,
                                          b_f, b_b, hf, hb);
    feats_proj<<<8192, 256, 0, stream>>>(hf, hb, w_out, b_out, feats);
    viterbi<<<64, 64, 0, stream>>>(feats, trans, out);
}